// Round 13
// baseline (141.135 us; speedup 1.0000x reference)
//
#include <hip/hip_runtime.h>
#include <hip/hip_bf16.h>

// HybridBCEDiceBoundaryLoss — scalar loss over logits/targets (32,1,512,512) fp32.
// loss = 0.3*BCE + 0.3*Dice + 0.2*BoundaryBCE + 0.2*LovaszHinge(per-image mean)
//
// Lovasz without sorting: counts-only histogram over e in (0,8), 1024 bins,
// suffix-scan ranks, bin-midpoint values (2nd-order accurate).
//
// R13: the 43-47us invariant across R4..R12 is latency x bytes-in-flight:
// every variant held ~1-1.5 KB of loads in flight per CU (VGPR-held loads cap
// MLP), giving ~2.9 B/cyc/CU over ~72 MB logical traffic. Fix: stage tiles
// into LDS with __builtin_amdgcn_global_load_lds width=16 (VGPR-free DMA,
// ~70 KB in flight per block), one barrier, then compute from LDS via
// ds_read_b128 + 3-row rolling register window + DPP halos (math unchanged).

#define NB      32
#define HH      512
#define WW      512
#define HW      (HH*WW)          // 262144
#define NTOT    (NB*HW)          // 8388608
#define K_BINS  1024
#define INV_H   128.0f           // K_BINS / 8.0 range
#define BIN_W   (1.0f/128.0f)
#define BPI     32               // blocks per image; block = 16 rows x 512 cols
#define LROWS   16
#define TROWS   18

struct Ws {
    unsigned cnt[NB*K_BINS];      // low16 = count_all, high16 = count_pos
    float    sy[NB];
    float    spy[NB];
    float    Pim[NB];
    float    bce_sum;
    float    bceE_sum;
    float    lov_sum;
    unsigned blkdone[NB];
    unsigned imgdone;
};

__device__ __forceinline__ void gload_lds16(const float* __restrict__ g, float* l) {
    __builtin_amdgcn_global_load_lds(
        (const __attribute__((address_space(1))) void*)g,
        (__attribute__((address_space(3))) void*)l, 16, 0, 0);
}

__device__ __forceinline__ float dpp_from_lower(float v) {   // lane L <- lane L-1
    const int r = __builtin_amdgcn_update_dpp(0, __float_as_int(v), 0x130, 0xF, 0xF, false);
    return __int_as_float(r);
}
__device__ __forceinline__ float dpp_from_upper(float v) {   // lane L <- lane L+1
    const int r = __builtin_amdgcn_update_dpp(0, __float_as_int(v), 0x138, 0xF, 0xF, false);
    return __int_as_float(r);
}
__device__ __forceinline__ float bcast_lane(float v, int lane) {
    return __int_as_float(__builtin_amdgcn_readlane(__float_as_int(v), lane));
}

// elementwise terms; returns -1 = no histogram hit, else (bin | 0x10000 if positive)
__device__ __forceinline__ int process_elem(float x, float y, float wsum,
                                            float& bce_s, float& bceE_s, float& sy_s,
                                            float& spy_s, float& P_s) {
    const float ax = fabsf(x);
    const float t  = __expf(-ax);                       // exp(-|x|)
    const float bce = fmaxf(x, 0.f) - x * y + __logf(1.f + t);
    const float inv = __builtin_amdgcn_rcpf(1.f + t);
    const float s = (x >= 0.f) ? inv : t * inv;         // sigmoid(x)
    const bool edge = (wsum > 0.5f) && (wsum < 8.5f);   // 1..8 of 9 ones

    bce_s  += bce;
    bceE_s += edge ? bce : 0.f;
    sy_s   += s * y;
    spy_s  += s + y;
    P_s    += y;

    const float e = 1.f - x * (2.f * y - 1.f);
    if (e > 0.f) {
        int b = (int)(e * INV_H);
        if (b > K_BINS - 1) b = K_BINS - 1;
        return (y > 0.5f) ? (b | 0x10000) : b;
    }
    return -1;
}

__global__ __launch_bounds__(256, 2) void kernelA(const float* __restrict__ logits,
                                                  const float* __restrict__ targets,
                                                  Ws* __restrict__ ws,
                                                  float* __restrict__ out) {
    __shared__ float    s_tgt[TROWS * WW];   // 36 KB
    __shared__ float    s_lgt[LROWS * WW];   // 32 KB
    __shared__ unsigned s_cnt[K_BINS];       // 4 KB
    __shared__ float    red[4][5];
    __shared__ unsigned sc_a[256];
    __shared__ unsigned sc_p[256];
    __shared__ double   dred[4];
    __shared__ unsigned s_flag, s_flag2;

    const int tid  = threadIdx.x;
    const int lane = tid & 63;
    const int wave = tid >> 6;

    for (int i = tid; i < K_BINS; i += 256) s_cnt[i] = 0u;

    const int img = blockIdx.x >> 5;            // 32 blocks per image
    const int blk = blockIdx.x & 31;
    const int r0  = blk * 16;                   // block rows r0..r0+15

    const float* __restrict__ tg = targets + img * HW;
    const float* __restrict__ lg = logits  + img * HW;

    // ---- DMA staging: VGPR-free, all in flight at once ----
    // targets: rows r0-1..r0+16 (clamped) -> slots 0..17; 36 x 1KB chunks, 9/wave
#pragma unroll
    for (int k = 0; k < 9; ++k) {
        const int c     = wave * 9 + k;
        const int rslot = c >> 1;
        int gr = r0 - 1 + rslot;
        gr = gr < 0 ? 0 : (gr > 511 ? 511 : gr);
        const int h = (c & 1) * 256;
        gload_lds16(tg + gr * WW + h + lane * 4, s_tgt + rslot * WW + h + lane * 4);
    }
    // logits: rows r0..r0+15 -> slots 0..15; 32 x 1KB chunks, 8/wave
#pragma unroll
    for (int k = 0; k < 8; ++k) {
        const int c     = wave * 8 + k;
        const int rslot = c >> 1;
        const int h     = (c & 1) * 256;
        gload_lds16(lg + (r0 + rslot) * WW + h + lane * 4, s_lgt + rslot * WW + h + lane * 4);
    }
    __syncthreads();   // drains DMA (vmcnt) + covers s_cnt init

#define HADD(expr) do { \
        const int _r = (expr); \
        if (_r >= 0) { \
            const unsigned _inc = (_r & 0x10000) ? 0x10001u : 1u; \
            (void)__hip_atomic_fetch_add(&s_cnt[_r & 0xFFFF], _inc, \
                                         __ATOMIC_RELAXED, __HIP_MEMORY_SCOPE_WORKGROUP); \
        } \
    } while (0)

    const int cA = 4 * lane;          // float cols 4l..4l+3
    const int cB = 256 + 4 * lane;    // float cols 256+4l..

    // wave handles output rows r0 + s0 .. r0 + s0 + 3
    const int s0 = wave * 4;

    float bce_s = 0.f, bceE_s = 0.f, sy_s = 0.f, spy_s = 0.f, P_s = 0.f;

    // rolling 3-row target window (slots s0+q .. s0+q+2)
    float4 Tt0 = *(const float4*)&s_tgt[(s0    ) * WW + cA];
    float4 Tt1 = *(const float4*)&s_tgt[(s0    ) * WW + cB];
    float4 Tm0 = *(const float4*)&s_tgt[(s0 + 1) * WW + cA];
    float4 Tm1 = *(const float4*)&s_tgt[(s0 + 1) * WW + cB];

#pragma unroll
    for (int q = 0; q < 4; ++q) {
        const float4 Tb0 = *(const float4*)&s_tgt[(s0 + q + 2) * WW + cA];
        const float4 Tb1 = *(const float4*)&s_tgt[(s0 + q + 2) * WW + cB];
        const float4 X0  = *(const float4*)&s_lgt[(s0 + q) * WW + cA];
        const float4 X1  = *(const float4*)&s_lgt[(s0 + q) * WW + cB];

        const int   grow = r0 + s0 + q;
        const float fa = (grow > 0)   ? 1.f : 0.f;
        const float fc = (grow < 511) ? 1.f : 0.f;

        float4 csA, csB;
        csA.x = fmaf(Tt0.x, fa, fmaf(Tb0.x, fc, Tm0.x));
        csA.y = fmaf(Tt0.y, fa, fmaf(Tb0.y, fc, Tm0.y));
        csA.z = fmaf(Tt0.z, fa, fmaf(Tb0.z, fc, Tm0.z));
        csA.w = fmaf(Tt0.w, fa, fmaf(Tb0.w, fc, Tm0.w));
        csB.x = fmaf(Tt1.x, fa, fmaf(Tb1.x, fc, Tm1.x));
        csB.y = fmaf(Tt1.y, fa, fmaf(Tb1.y, fc, Tm1.y));
        csB.z = fmaf(Tt1.z, fa, fmaf(Tb1.z, fc, Tm1.z));
        csB.w = fmaf(Tt1.w, fa, fmaf(Tb1.w, fc, Tm1.w));

        const float upA  = dpp_from_lower(csA.w);
        const float dnA  = dpp_from_upper(csA.x);
        const float upB  = dpp_from_lower(csB.w);
        const float dnB  = dpp_from_upper(csB.x);
        const float bc0  = bcast_lane(csB.x, 0);
        const float bc63 = bcast_lane(csA.w, 63);
        const float LA = (lane == 0)  ? 0.f  : upA;
        const float RA = (lane == 63) ? bc0  : dnA;
        const float LB = (lane == 0)  ? bc63 : upB;
        const float RB = (lane == 63) ? 0.f  : dnB;

        HADD(process_elem(X0.x, Tm0.x, LA + csA.x + csA.y,    bce_s, bceE_s, sy_s, spy_s, P_s));
        HADD(process_elem(X0.y, Tm0.y, csA.x + csA.y + csA.z, bce_s, bceE_s, sy_s, spy_s, P_s));
        HADD(process_elem(X0.z, Tm0.z, csA.y + csA.z + csA.w, bce_s, bceE_s, sy_s, spy_s, P_s));
        HADD(process_elem(X0.w, Tm0.w, csA.z + csA.w + RA,    bce_s, bceE_s, sy_s, spy_s, P_s));
        HADD(process_elem(X1.x, Tm1.x, LB + csB.x + csB.y,    bce_s, bceE_s, sy_s, spy_s, P_s));
        HADD(process_elem(X1.y, Tm1.y, csB.x + csB.y + csB.z, bce_s, bceE_s, sy_s, spy_s, P_s));
        HADD(process_elem(X1.z, Tm1.z, csB.y + csB.z + csB.w, bce_s, bceE_s, sy_s, spy_s, P_s));
        HADD(process_elem(X1.w, Tm1.w, csB.z + csB.w + RB,    bce_s, bceE_s, sy_s, spy_s, P_s));

        Tt0 = Tm0; Tt1 = Tm1; Tm0 = Tb0; Tm1 = Tb1;
    }
#undef HADD
    __syncthreads();

    // flush histogram to global (packed counts)
    unsigned* g_c = ws->cnt + img * K_BINS;
    for (int i = tid; i < K_BINS; i += 256) {
        const unsigned cpk = s_cnt[i];
        if (cpk) atomicAdd(&g_c[i], cpk);
    }

    // block reduction of 5 accumulators
    for (int off = 32; off; off >>= 1) {
        bce_s  += __shfl_down(bce_s, off);
        bceE_s += __shfl_down(bceE_s, off);
        sy_s   += __shfl_down(sy_s, off);
        spy_s  += __shfl_down(spy_s, off);
        P_s    += __shfl_down(P_s, off);
    }
    if (lane == 0) {
        red[wave][0] = bce_s; red[wave][1] = bceE_s; red[wave][2] = sy_s;
        red[wave][3] = spy_s; red[wave][4] = P_s;
    }
    __syncthreads();
    if (tid == 0) {
        float a = 0.f, b = 0.f, c2 = 0.f, d = 0.f, e2 = 0.f;
        for (int w = 0; w < 4; ++w) {
            a += red[w][0]; b += red[w][1]; c2 += red[w][2];
            d += red[w][3]; e2 += red[w][4];
        }
        atomicAdd(&ws->bce_sum, a);
        atomicAdd(&ws->bceE_sum, b);
        atomicAdd(&ws->sy[img], c2);
        atomicAdd(&ws->spy[img], d);
        atomicAdd(&ws->Pim[img], e2);
        __threadfence();
        const unsigned dcnt = atomicAdd(&ws->blkdone[img], 1u);
        s_flag = (dcnt == (unsigned)(BPI - 1)) ? 1u : 0u;
    }
    __syncthreads();

    // ---- fused per-image Lovasz scan: last block of this image only ----
    if (s_flag) {
        unsigned* cn = ws->cnt + img * K_BINS;

        unsigned la[4], lp[4];
        float    me[4];
        unsigned tot_a = 0, tot_p = 0;
#pragma unroll
        for (int j = 0; j < 4; ++j) {
            const int k = K_BINS - 1 - (tid * 4 + j);
            const unsigned cpk = atomicAdd(&cn[k], 0u);   // coherent RMW-read
            la[j] = cpk & 0xFFFFu; lp[j] = cpk >> 16;
            me[j] = ((float)k + 0.5f) * BIN_W;
            tot_a += la[j]; tot_p += lp[j];
        }

        sc_a[tid] = tot_a; sc_p[tid] = tot_p;
        __syncthreads();
        for (int off = 1; off < 256; off <<= 1) {
            unsigned va = (tid >= off) ? sc_a[tid - off] : 0u;
            unsigned vp = (tid >= off) ? sc_p[tid - off] : 0u;
            __syncthreads();
            sc_a[tid] += va; sc_p[tid] += vp;
            __syncthreads();
        }
        const unsigned excl_a = sc_a[tid] - tot_a;
        const unsigned excl_p = sc_p[tid] - tot_p;

        const double P = (double)atomicAdd(&ws->Pim[img], 0.f);
        double run_a = (double)excl_a, run_p = (double)excl_p;
        double contrib = 0.0;
#pragma unroll
        for (int j = 0; j < 4; ++j) {
            const double m = (double)la[j];
            const double p = (double)lp[j];
            if (la[j]) {
                const double u = P + (run_a + 0.5 * m) - (run_p + 0.5 * p);
                const double c = run_p + 0.5 * p;
                contrib += (double)(lp[j] * me[j]) / u;                       // positives
                const double den = u * (u - 1.0);
                if (den > 0.0)
                    contrib += (double)((la[j] - lp[j]) * me[j]) * (P - c) / den;  // negatives
            }
            run_a += m; run_p += p;
        }

        for (int off = 32; off; off >>= 1) contrib += __shfl_down(contrib, off);
        if (lane == 0) dred[wave] = contrib;
        __syncthreads();
        if (tid == 0) {
            const double tot = dred[0] + dred[1] + dred[2] + dred[3];
            atomicAdd(&ws->lov_sum, (float)tot);
            __threadfence();
            const unsigned d32 = atomicAdd(&ws->imgdone, 1u);
            s_flag2 = (d32 == (unsigned)(NB - 1)) ? 1u : 0u;
        }
        __syncthreads();

        // ---- final combine: the very last image's scan block, wave 0 ----
        if (s_flag2 && wave == 0) {
            float dsum = 0.f;
            if (lane < NB) {
                const float syv  = atomicAdd(&ws->sy[lane], 0.f);
                const float spyv = atomicAdd(&ws->spy[lane], 0.f);
                dsum = 2.f * syv / (spyv + 1e-7f);
            }
            for (int off = 32; off; off >>= 1) dsum += __shfl_down(dsum, off);
            if (lane == 0) {
                const float bsum = atomicAdd(&ws->bce_sum, 0.f);
                const float besm = atomicAdd(&ws->bceE_sum, 0.f);
                const float lsum = atomicAdd(&ws->lov_sum, 0.f);
                const float invN = 1.f / (float)NTOT;
                const float bce      = bsum * invN;
                const float boundary = (bsum + 2.f * besm) * invN;
                const float dice     = 1.f - dsum / (float)NB;
                const float lov      = lsum / (float)NB;
                out[0] = 0.3f * bce + 0.3f * dice + 0.2f * boundary + 0.2f * lov;
            }
        }
    }
}

extern "C" void kernel_launch(void* const* d_in, const int* in_sizes, int n_in,
                              void* d_out, int out_size, void* d_ws, size_t ws_size,
                              hipStream_t stream) {
    const float* logits  = (const float*)d_in[0];
    const float* targets = (const float*)d_in[1];
    float* out = (float*)d_out;
    Ws* ws = (Ws*)d_ws;

    (void)hipMemsetAsync(d_ws, 0, sizeof(Ws), stream);
    kernelA<<<NB * BPI, 256, 0, stream>>>(logits, targets, ws, out);
}